// Round 9
// baseline (285.205 us; speedup 1.0000x reference)
//
#include <hip/hip_runtime.h>

// GridPoolingLayer: per-cell mean pooling where cells are rectangles defined
// by rising edges of h_mask (rows) and v_mask (cols). H=W=768, C=64, fp32.
//
// R6 (2nd attempt; prior bench died on container acquisition — infra):
//   SEPARABLE two-stage reduction (row-pool then col-pool).
//   row_pool : dense streaming pass. Block owns (row-segment rid, 16-px
//              stripe); thread owns (x, channel-quad) and sums its column
//              over the segment's rows with 4 clamped/masked loads in
//              flight. Fully coalesced 151 MB read at HBM BW -> the
//              HBM-latency gather is eliminated from the big pass.
//   col_pool : wave per cell, gathers along x over rowsum (L3-resident,
//              typically ONE load per lane group), descriptor-prefetch
//              pipelined. Writes 256 B mean per cell.
//   bcast_ws : dense broadcast, nontemporal stores (unchanged from R5).
//   Fallbacks: ws too small for rowsum -> R5 path (cell_mean3+bcast_ws);
//              ws too small for means  -> anchor path.

#define GH 768
#define GW 768
#define MAXSEG 385   // alternating mask gives 384 rising edges -> 385 segments
#define NSTRIPE 48   // 768 / 16 px per stripe

typedef __attribute__((ext_vector_type(4))) float f32x4;

enum {
    OFF_ROWSTART = 0,
    OFF_ROWEND   = OFF_ROWSTART + MAXSEG,
    OFF_COLSTART = OFF_ROWEND + MAXSEG,
    OFF_COLEND   = OFF_COLSTART + MAXSEG,
    OFF_NROWS    = OFF_COLEND + MAXSEG,
    OFF_NCOLS    = OFF_NROWS + 1,
    OFF_ROWID    = OFF_NCOLS + 1,        // [GH]  row-segment id per y
    OFF_COLID    = OFF_ROWID + GH,       // [GW]  col-segment id per x
    OFF_MEANS    = 4096,                 // int offset; float4 region follows
};
#define MEANS_F4  ((size_t)MAXSEG * MAXSEG * 16)  // means: cell x 16 float4
#define ROWSUM_F4 ((size_t)MAXSEG * GW * 16)      // rowsum: rid x 768 x 16 f4

__global__ __launch_bounds__(768) void seg_scan(const int* __restrict__ h_mask,
                                                const int* __restrict__ v_mask,
                                                int* __restrict__ ws) {
    __shared__ int s[GH];
    const int i = threadIdx.x;
    const bool is_row = (blockIdx.x == 0);
    const int* m = is_row ? h_mask : v_mask;

    int mi = m[i];
    int rising = 0;
    if (i > 0) rising = (mi == 1 && m[i - 1] == 0) ? 1 : 0;  // rising[0] forced 0
    s[i] = rising;
    __syncthreads();

    for (int off = 1; off < GH; off <<= 1) {
        int add = (i >= off) ? s[i - off] : 0;
        __syncthreads();
        s[i] += add;
        __syncthreads();
    }

    const int seg  = s[i];
    const int segL = (i == 0)      ? -1 : s[i - 1];
    const int segR = (i == GH - 1) ? -2 : s[i + 1];

    ws[(is_row ? OFF_ROWID : OFF_COLID) + i] = seg;   // per-pixel segment id

    int* start = ws + (is_row ? OFF_ROWSTART : OFF_COLSTART);
    int* end   = ws + (is_row ? OFF_ROWEND   : OFF_COLEND);
    if (seg != segL) start[seg] = i;
    if (seg != segR) end[seg]   = i + 1;
    if (i == GH - 1) ws[is_row ? OFF_NROWS : OFF_NCOLS] = seg + 1;
}

// Stage A: rowsum[rid][x][cq] = sum over y in rowseg(rid) of in[y][x][cq].
// Block strides over (rid, stripe) pairs; thread owns (x, cq); 4 y-loads in
// flight per iteration (clamped addr, masked add). Next pair's descriptors
// prefetched before the y-loop.
__global__ __launch_bounds__(256) void row_pool(const float4* __restrict__ in,
                                                float4* __restrict__ rowsum,
                                                const int* __restrict__ ws) {
    const int nrows = ws[OFF_NROWS];
    const int pairs = nrows * NSTRIPE;
    const int xl = threadIdx.x >> 4;     // 0..15: pixel within stripe
    const int cq = threadIdx.x & 15;     // channel quad

    int pair = blockIdx.x;
    if (pair >= pairs) return;
    int rid = pair / NSTRIPE;
    int st  = pair - rid * NSTRIPE;
    int y0  = ws[OFF_ROWSTART + rid];
    int y1  = ws[OFF_ROWEND   + rid];

    while (true) {
        // prefetch next pair's descriptors (hide L2 latency under the gather)
        const int npair = pair + gridDim.x;
        const bool have_next = (npair < pairs);
        const int pp   = have_next ? npair : 0;
        const int nrid = pp / NSTRIPE;
        const int nst  = pp - nrid * NSTRIPE;
        const int ny0  = ws[OFF_ROWSTART + nrid];
        const int ny1  = ws[OFF_ROWEND   + nrid];

        const int x    = st * 16 + xl;
        const int ylim = y1 - 1;
        float4 acc = make_float4(0.f, 0.f, 0.f, 0.f);

        for (int y = y0; y < y1; y += 4) {
            const int yB = min(y + 1, ylim);
            const int yC = min(y + 2, ylim);
            const int yD = min(y + 3, ylim);
            // 4 loads in one BB -> one waitcnt region, 4 requests in flight
            const float4 vA = in[((size_t)y  * GW + x) * 16 + cq];
            const float4 vB = in[((size_t)yB * GW + x) * 16 + cq];
            const float4 vC = in[((size_t)yC * GW + x) * 16 + cq];
            const float4 vD = in[((size_t)yD * GW + x) * 16 + cq];
            const bool mB = (y + 1 < y1), mC = (y + 2 < y1), mD = (y + 3 < y1);
            acc.x += vA.x;  acc.y += vA.y;  acc.z += vA.z;  acc.w += vA.w;
            acc.x += mB ? vB.x : 0.f;  acc.y += mB ? vB.y : 0.f;
            acc.z += mB ? vB.z : 0.f;  acc.w += mB ? vB.w : 0.f;
            acc.x += mC ? vC.x : 0.f;  acc.y += mC ? vC.y : 0.f;
            acc.z += mC ? vC.z : 0.f;  acc.w += mC ? vC.w : 0.f;
            acc.x += mD ? vD.x : 0.f;  acc.y += mD ? vD.y : 0.f;
            acc.z += mD ? vD.z : 0.f;  acc.w += mD ? vD.w : 0.f;
        }

        rowsum[((size_t)rid * GW + x) * 16 + cq] = acc;

        if (!have_next) break;
        pair = npair; rid = nrid; st = nst; y0 = ny0; y1 = ny1;
    }
}

// Stage B: means[cell] = (sum over x in colseg of rowsum[rid][x]) / area.
// One wave per cell; lane = pg*16+cq; pg strides x by 4. rowsum is
// L3-resident -> short round-trips; next cell's descriptors prefetched.
__global__ __launch_bounds__(256) void col_pool(const float4* __restrict__ rowsum,
                                                float4* __restrict__ means,
                                                const int* __restrict__ ws) {
    const int nrows  = ws[OFF_NROWS];
    const int ncols  = ws[OFF_NCOLS];
    const int ncells = nrows * ncols;

    const int wave   = blockIdx.x * 4 + (threadIdx.x >> 6);
    const int nwaves = gridDim.x * 4;
    const int lane   = threadIdx.x & 63;
    const int pg     = lane >> 4;
    const int cq     = lane & 15;

    int cell = wave;
    if (cell >= ncells) return;
    int rid = cell / ncols;
    int cid = cell - rid * ncols;
    int x0  = ws[OFF_COLSTART + cid];
    int x1  = ws[OFF_COLEND   + cid];
    int h   = ws[OFF_ROWEND + rid] - ws[OFF_ROWSTART + rid];

    while (true) {
        const int ncell = cell + nwaves;
        const bool have_next = (ncell < ncells);
        const int cc    = have_next ? ncell : 0;
        const int nrid  = cc / ncols;
        const int ncid  = cc - nrid * ncols;
        const int nx0   = ws[OFF_COLSTART + ncid];
        const int nx1   = ws[OFF_COLEND   + ncid];
        const int nh    = ws[OFF_ROWEND + nrid] - ws[OFF_ROWSTART + nrid];

        float4 acc = make_float4(0.f, 0.f, 0.f, 0.f);
        const size_t rb = (size_t)rid * GW * 16 + cq;
        for (int x = x0 + pg; x < x1; x += 4) {
            const float4 v = rowsum[rb + (size_t)x * 16];
            acc.x += v.x; acc.y += v.y; acc.z += v.z; acc.w += v.w;
        }

        #pragma unroll
        for (int msk = 16; msk < 64; msk <<= 1) {   // combine the 4 pg groups
            acc.x += __shfl_xor(acc.x, msk, 64);
            acc.y += __shfl_xor(acc.y, msk, 64);
            acc.z += __shfl_xor(acc.z, msk, 64);
            acc.w += __shfl_xor(acc.w, msk, 64);
        }

        if (lane < 16) {
            const float inv = 1.f / (float)(h * (x1 - x0));
            means[cell * 16 + lane] = make_float4(acc.x * inv, acc.y * inv,
                                                  acc.z * inv, acc.w * inv);
        }

        if (!have_next) break;
        cell = ncell; rid = nrid; cid = ncid; x0 = nx0; x1 = nx1; h = nh;
    }
}

// ---- R5 fallback kernel (means path without rowsum space) ----
__global__ __launch_bounds__(256) void cell_mean3(const float4* __restrict__ in,
                                                  float4* __restrict__ dst,
                                                  const int* __restrict__ ws,
                                                  int anchor_mode) {
    const int nrows  = ws[OFF_NROWS];
    const int ncols  = ws[OFF_NCOLS];
    const int ncells = nrows * ncols;

    const int wave   = blockIdx.x * 4 + (threadIdx.x >> 6);
    const int nwaves = gridDim.x * 4;
    const int lane   = threadIdx.x & 63;
    const int pg     = lane >> 4;
    const int cq     = lane & 15;

    int cell = wave;
    if (cell >= ncells) return;
    int br = cell / ncols;
    int bc = cell - br * ncols;
    int y0 = ws[OFF_ROWSTART + br];
    int y1 = ws[OFF_ROWEND   + br];
    int x0 = ws[OFF_COLSTART + bc];
    int x1 = ws[OFF_COLEND   + bc];

    while (true) {
        const int ncell = cell + nwaves;
        const bool have_next = (ncell < ncells);
        const int cc  = have_next ? ncell : 0;
        const int nbr = cc / ncols;
        const int nbc = cc - nbr * ncols;
        const int ny0 = ws[OFF_ROWSTART + nbr];
        const int ny1 = ws[OFF_ROWEND   + nbr];
        const int nx0 = ws[OFF_COLSTART + nbc];
        const int nx1 = ws[OFF_COLEND   + nbc];

        const int w    = x1 - x0;
        const int npx  = w * (y1 - y0);
        const int q    = (npx + 3) >> 2;
        const int base = pg * q;
        int len = min(base + q, npx) - base;
        const int ylim = y1 - 1;

        const unsigned ub = (unsigned)base;
        const unsigned uy = ub / (unsigned)w;
        int yy = y0 + (int)uy;
        int xx = x0 + (int)(ub - uy * (unsigned)w);

        float4 acc = make_float4(0.f, 0.f, 0.f, 0.f);
        while (len > 0) {
            const int xA = xx;           const int yAc = min(yy, ylim);
            int xB = xx + 1, yB = yy;  if (xB >= x1) { xB = x0; ++yB; }
            const int yBc = min(yB, ylim);
            int xC = xB + 1, yC = yB;  if (xC >= x1) { xC = x0; ++yC; }
            const int yCc = min(yC, ylim);
            int xD = xC + 1, yD = yC;  if (xD >= x1) { xD = x0; ++yD; }
            const int yDc = min(yD, ylim);

            const float4 vA = in[(yAc * GW + xA) * 16 + cq];
            const float4 vB = in[(yBc * GW + xB) * 16 + cq];
            const float4 vC = in[(yCc * GW + xC) * 16 + cq];
            const float4 vD = in[(yDc * GW + xD) * 16 + cq];

            const bool mB = (1 < len), mC = (2 < len), mD = (3 < len);
            acc.x += vA.x;  acc.y += vA.y;  acc.z += vA.z;  acc.w += vA.w;
            acc.x += mB ? vB.x : 0.f;  acc.y += mB ? vB.y : 0.f;
            acc.z += mB ? vB.z : 0.f;  acc.w += mB ? vB.w : 0.f;
            acc.x += mC ? vC.x : 0.f;  acc.y += mC ? vC.y : 0.f;
            acc.z += mC ? vC.z : 0.f;  acc.w += mC ? vC.w : 0.f;
            acc.x += mD ? vD.x : 0.f;  acc.y += mD ? vD.y : 0.f;
            acc.z += mD ? vD.z : 0.f;  acc.w += mD ? vD.w : 0.f;

            int xE = xD + 1, yE = yD;  if (xE >= x1) { xE = x0; ++yE; }
            xx = xE; yy = yE;
            len -= 4;
        }

        #pragma unroll
        for (int msk = 16; msk < 64; msk <<= 1) {
            acc.x += __shfl_xor(acc.x, msk, 64);
            acc.y += __shfl_xor(acc.y, msk, 64);
            acc.z += __shfl_xor(acc.z, msk, 64);
            acc.w += __shfl_xor(acc.w, msk, 64);
        }

        if (lane < 16) {
            const float inv = 1.f / (float)npx;
            float4 mean = make_float4(acc.x * inv, acc.y * inv,
                                      acc.z * inv, acc.w * inv);
            const int oidx = anchor_mode ? (y0 * GW + x0) * 16 + lane
                                         : cell * 16 + lane;
            dst[oidx] = mean;
        }

        if (!have_next) break;
        cell = ncell;
        y0 = ny0; y1 = ny1; x0 = nx0; x1 = nx1;
    }
}

// Dense streaming broadcast, means from ws. NONTEMPORAL out stores (147 MB
// write-once). Grid MUST be 2048x256: 768*768*16 / (2048*256) = 18/thread.
__global__ __launch_bounds__(256) void bcast_ws(float4* __restrict__ out,
                                                const float4* __restrict__ means,
                                                const int* __restrict__ ws) {
    const int ncols = ws[OFF_NCOLS];
    int g = blockIdx.x * 256 + threadIdx.x;
    #pragma unroll 6
    for (int it = 0; it < 18; ++it, g += 2048 * 256) {
        const int p  = g >> 4;
        const int cq = g & 15;
        const int y  = p / GW;              // constant divisor -> magic mul
        const int x  = p - y * GW;
        const int rid = ws[OFF_ROWID + y];
        const int cid = ws[OFF_COLID + x];
        const float4 v = means[(rid * ncols + cid) * 16 + cq];
        __builtin_nontemporal_store(*(const f32x4*)&v, (f32x4*)&out[g]);
    }
}

// Last-resort broadcast: means live at each cell's anchor pixel inside out.
__global__ __launch_bounds__(256) void bcast_anchor(float4* out,
                                                    const int* __restrict__ ws) {
    int g = blockIdx.x * 256 + threadIdx.x;
    for (int it = 0; it < 18; ++it, g += 2048 * 256) {
        const int p  = g >> 4;
        const int cq = g & 15;
        const int y  = p / GW;
        const int x  = p - y * GW;
        const int rid = ws[OFF_ROWID + y];
        const int cid = ws[OFF_COLID + x];
        const int ya  = ws[OFF_ROWSTART + rid];
        const int xa  = ws[OFF_COLSTART + cid];
        out[g] = out[(ya * GW + xa) * 16 + cq];
    }
}

extern "C" void kernel_launch(void* const* d_in, const int* in_sizes, int n_in,
                              void* d_out, int out_size, void* d_ws, size_t ws_size,
                              hipStream_t stream) {
    const float* in  = (const float*)d_in[0];   // [1,768,768,64] fp32
    const int* hmask = (const int*)d_in[1];     // [1,768] int32
    const int* vmask = (const int*)d_in[2];     // [1,768] int32
    float* out = (float*)d_out;                 // [1,768,768,64] fp32
    int* ws = (int*)d_ws;

    seg_scan<<<2, GH, 0, stream>>>(hmask, vmask, ws);

    const size_t need_means = (size_t)OFF_MEANS * 4 + MEANS_F4 * 16;
    const size_t need_full  = need_means + ROWSUM_F4 * 16;

    if (ws_size >= need_full) {
        float4* means  = (float4*)(ws + OFF_MEANS);
        float4* rowsum = means + MEANS_F4;
        row_pool<<<2048, 256, 0, stream>>>((const float4*)in, rowsum, ws);
        col_pool<<<2048, 256, 0, stream>>>(rowsum, means, ws);
        bcast_ws<<<2048, 256, 0, stream>>>((float4*)out, means, ws);
    } else if (ws_size >= need_means) {
        float4* means = (float4*)(ws + OFF_MEANS);
        cell_mean3<<<2048, 256, 0, stream>>>((const float4*)in, means, ws, 0);
        bcast_ws<<<2048, 256, 0, stream>>>((float4*)out, means, ws);
    } else {
        cell_mean3<<<2048, 256, 0, stream>>>((const float4*)in, (float4*)out, ws, 1);
        bcast_anchor<<<2048, 256, 0, stream>>>((float4*)out, ws);
    }
}

// Round 10
// 272.390 us; speedup vs baseline: 1.0470x; 1.0470x over previous
//
#include <hip/hip_runtime.h>

// GridPoolingLayer: per-cell mean pooling where cells are rectangles defined
// by rising edges of h_mask (rows) and v_mask (cols). H=W=768, C=64, fp32.
//
// R7: REVERT separable (R6 regressed 271->285: +85MB traffic, same short-burst
// latency shape). Back to R5 split structure, with DUAL-CELL gather:
//   cell_mean4: each wave processes cells (c, c+nwaves) SIMULTANEOUSLY —
//     both gathers issue in one basic block -> 8 loads in flight per
//     round-trip (vs 4), halving the serial chain count per wave
//     (4.5 -> 2.25 chains). Input loads are NONTEMPORAL (151 MB read-once;
//     keep L2 for descriptors/means). Next pair's descriptors prefetched
//     before the gather (R5, measured +).
//   bcast_ws: dense streaming broadcast, nontemporal stores (R5, measured +).
//   Fallback (ws too small for means): anchor-pixel path.

#define GH 768
#define GW 768
#define MAXSEG 385  // alternating mask gives 384 rising edges -> 385 segments

typedef __attribute__((ext_vector_type(4))) float f32x4;

enum {
    OFF_ROWSTART = 0,
    OFF_ROWEND   = OFF_ROWSTART + MAXSEG,
    OFF_COLSTART = OFF_ROWEND + MAXSEG,
    OFF_COLEND   = OFF_COLSTART + MAXSEG,
    OFF_NROWS    = OFF_COLEND + MAXSEG,
    OFF_NCOLS    = OFF_NROWS + 1,
    OFF_ROWID    = OFF_NCOLS + 1,        // [GH]  row-segment id per y
    OFF_COLID    = OFF_ROWID + GH,       // [GW]  col-segment id per x
    OFF_MEANS    = 4096,                 // float4 means[cell][16] follows
};
#define MEANS_F4 ((size_t)MAXSEG * MAXSEG * 16)

__global__ __launch_bounds__(768) void seg_scan(const int* __restrict__ h_mask,
                                                const int* __restrict__ v_mask,
                                                int* __restrict__ ws) {
    __shared__ int s[GH];
    const int i = threadIdx.x;
    const bool is_row = (blockIdx.x == 0);
    const int* m = is_row ? h_mask : v_mask;

    int mi = m[i];
    int rising = 0;
    if (i > 0) rising = (mi == 1 && m[i - 1] == 0) ? 1 : 0;  // rising[0] forced 0
    s[i] = rising;
    __syncthreads();

    for (int off = 1; off < GH; off <<= 1) {
        int add = (i >= off) ? s[i - off] : 0;
        __syncthreads();
        s[i] += add;
        __syncthreads();
    }

    const int seg  = s[i];
    const int segL = (i == 0)      ? -1 : s[i - 1];
    const int segR = (i == GH - 1) ? -2 : s[i + 1];

    ws[(is_row ? OFF_ROWID : OFF_COLID) + i] = seg;   // per-pixel segment id

    int* start = ws + (is_row ? OFF_ROWSTART : OFF_COLSTART);
    int* end   = ws + (is_row ? OFF_ROWEND   : OFF_COLEND);
    if (seg != segL) start[seg] = i;
    if (seg != segR) end[seg]   = i + 1;
    if (i == GH - 1) ws[is_row ? OFF_NROWS : OFF_NCOLS] = seg + 1;
}

// Dual-cell gather. lane = pg*16 + cq; group pg owns a contiguous quarter of
// each cell's flat pixel range. Per loop iteration: 4 clamped/masked loads
// for cell A + 4 for cell B in ONE basic block -> 8 requests in flight.
// anchor_mode==0: mean -> dst[cell*16 + cq]       (dst = means region of ws)
// anchor_mode==1: mean -> dst[(y0*GW+x0)*16 + cq] (dst = out, anchor pixel)
__global__ __launch_bounds__(256) void cell_mean4(const float4* __restrict__ in,
                                                  float4* __restrict__ dst,
                                                  const int* __restrict__ ws,
                                                  int anchor_mode) {
    const int nrows  = ws[OFF_NROWS];
    const int ncols  = ws[OFF_NCOLS];
    const int ncells = nrows * ncols;

    const int wave   = blockIdx.x * 4 + (threadIdx.x >> 6);
    const int nwaves = gridDim.x * 4;
    const int lane   = threadIdx.x & 63;
    const int pg     = lane >> 4;
    const int cq     = lane & 15;

    int cellA = wave;
    if (cellA >= ncells) return;

    // descriptors for the first pair (A = cellA, B = cellA+nwaves clamped)
    {
    }
    int cb0   = (cellA + nwaves < ncells) ? cellA + nwaves : cellA;
    int brA = cellA / ncols, bcA = cellA - brA * ncols;
    int brB = cb0   / ncols, bcB = cb0   - brB * ncols;
    int y0A = ws[OFF_ROWSTART + brA], y1A = ws[OFF_ROWEND + brA];
    int x0A = ws[OFF_COLSTART + bcA], x1A = ws[OFF_COLEND + bcA];
    int y0B = ws[OFF_ROWSTART + brB], y1B = ws[OFF_ROWEND + brB];
    int x0B = ws[OFF_COLSTART + bcB], x1B = ws[OFF_COLEND + bcB];

    while (true) {
        const bool hasB      = (cellA + nwaves) < ncells;
        const int  cellB     = hasB ? cellA + nwaves : cellA;
        const int  nextA     = cellA + 2 * nwaves;
        const bool have_next = nextA < ncells;

        // ---- prefetch NEXT pair's descriptors (hide under gather HBM lat) --
        const int pa  = have_next ? nextA : 0;
        const int pbn = pa + nwaves;
        const int pb  = (pbn < ncells) ? pbn : pa;
        const int nbrA = pa / ncols, nbcA = pa - nbrA * ncols;
        const int nbrB = pb / ncols, nbcB = pb - nbrB * ncols;
        const int py0A = ws[OFF_ROWSTART + nbrA], py1A = ws[OFF_ROWEND + nbrA];
        const int px0A = ws[OFF_COLSTART + nbcA], px1A = ws[OFF_COLEND + nbcA];
        const int py0B = ws[OFF_ROWSTART + nbrB], py1B = ws[OFF_ROWEND + nbrB];
        const int px0B = ws[OFF_COLSTART + nbcB], px1B = ws[OFF_COLEND + nbcB];

        // ---- gather setup for both cells ----
        const int wA = x1A - x0A, npxA = wA * (y1A - y0A);
        const int wB = x1B - x0B, npxB = wB * (y1B - y0B);
        const int qA = (npxA + 3) >> 2, qB = (npxB + 3) >> 2;
        int lenA = min(pg * qA + qA, npxA) - pg * qA;   // may be <= 0
        int lenB = min(pg * qB + qB, npxB) - pg * qB;
        const int ylimA = y1A - 1, ylimB = y1B - 1;

        const unsigned ubA = (unsigned)(pg * qA);
        const unsigned uyA = ubA / (unsigned)wA;
        int yyA = y0A + (int)uyA, xxA = x0A + (int)(ubA - uyA * (unsigned)wA);
        const unsigned ubB = (unsigned)(pg * qB);
        const unsigned uyB = ubB / (unsigned)wB;
        int yyB = y0B + (int)uyB, xxB = x0B + (int)(ubB - uyB * (unsigned)wB);

        float4 accA = make_float4(0.f, 0.f, 0.f, 0.f);
        float4 accB = make_float4(0.f, 0.f, 0.f, 0.f);

        while (lenA > 0 || lenB > 0) {
            // ---- side A: 4 consecutive flat pixels, chained wrap ----
            const int aX0 = xxA;          const int aY0 = min(yyA, ylimA);
            int aX1 = xxA + 1, aT1 = yyA; if (aX1 >= x1A) { aX1 = x0A; ++aT1; }
            const int aY1 = min(aT1, ylimA);
            int aX2 = aX1 + 1, aT2 = aT1; if (aX2 >= x1A) { aX2 = x0A; ++aT2; }
            const int aY2 = min(aT2, ylimA);
            int aX3 = aX2 + 1, aT3 = aT2; if (aX3 >= x1A) { aX3 = x0A; ++aT3; }
            const int aY3 = min(aT3, ylimA);
            // ---- side B ----
            const int bX0 = xxB;          const int bY0 = min(yyB, ylimB);
            int bX1 = xxB + 1, bT1 = yyB; if (bX1 >= x1B) { bX1 = x0B; ++bT1; }
            const int bY1 = min(bT1, ylimB);
            int bX2 = bX1 + 1, bT2 = bT1; if (bX2 >= x1B) { bX2 = x0B; ++bT2; }
            const int bY2 = min(bT2, ylimB);
            int bX3 = bX2 + 1, bT3 = bT2; if (bX3 >= x1B) { bX3 = x0B; ++bT3; }
            const int bY3 = min(bT3, ylimB);

            // ---- 8 nontemporal loads in ONE basic block -> 8 in flight ----
            const f32x4 vA0 = __builtin_nontemporal_load((const f32x4*)&in[(aY0 * GW + aX0) * 16 + cq]);
            const f32x4 vA1 = __builtin_nontemporal_load((const f32x4*)&in[(aY1 * GW + aX1) * 16 + cq]);
            const f32x4 vA2 = __builtin_nontemporal_load((const f32x4*)&in[(aY2 * GW + aX2) * 16 + cq]);
            const f32x4 vA3 = __builtin_nontemporal_load((const f32x4*)&in[(aY3 * GW + aX3) * 16 + cq]);
            const f32x4 vB0 = __builtin_nontemporal_load((const f32x4*)&in[(bY0 * GW + bX0) * 16 + cq]);
            const f32x4 vB1 = __builtin_nontemporal_load((const f32x4*)&in[(bY1 * GW + bX1) * 16 + cq]);
            const f32x4 vB2 = __builtin_nontemporal_load((const f32x4*)&in[(bY2 * GW + bX2) * 16 + cq]);
            const f32x4 vB3 = __builtin_nontemporal_load((const f32x4*)&in[(bY3 * GW + bX3) * 16 + cq]);

            const bool a0 = (0 < lenA), a1 = (1 < lenA), a2 = (2 < lenA), a3 = (3 < lenA);
            const bool b0 = (0 < lenB), b1 = (1 < lenB), b2 = (2 < lenB), b3 = (3 < lenB);
            accA.x += a0 ? vA0.x : 0.f;  accA.y += a0 ? vA0.y : 0.f;
            accA.z += a0 ? vA0.z : 0.f;  accA.w += a0 ? vA0.w : 0.f;
            accA.x += a1 ? vA1.x : 0.f;  accA.y += a1 ? vA1.y : 0.f;
            accA.z += a1 ? vA1.z : 0.f;  accA.w += a1 ? vA1.w : 0.f;
            accA.x += a2 ? vA2.x : 0.f;  accA.y += a2 ? vA2.y : 0.f;
            accA.z += a2 ? vA2.z : 0.f;  accA.w += a2 ? vA2.w : 0.f;
            accA.x += a3 ? vA3.x : 0.f;  accA.y += a3 ? vA3.y : 0.f;
            accA.z += a3 ? vA3.z : 0.f;  accA.w += a3 ? vA3.w : 0.f;
            accB.x += b0 ? vB0.x : 0.f;  accB.y += b0 ? vB0.y : 0.f;
            accB.z += b0 ? vB0.z : 0.f;  accB.w += b0 ? vB0.w : 0.f;
            accB.x += b1 ? vB1.x : 0.f;  accB.y += b1 ? vB1.y : 0.f;
            accB.z += b1 ? vB1.z : 0.f;  accB.w += b1 ? vB1.w : 0.f;
            accB.x += b2 ? vB2.x : 0.f;  accB.y += b2 ? vB2.y : 0.f;
            accB.z += b2 ? vB2.z : 0.f;  accB.w += b2 ? vB2.w : 0.f;
            accB.x += b3 ? vB3.x : 0.f;  accB.y += b3 ? vB3.y : 0.f;
            accB.z += b3 ? vB3.z : 0.f;  accB.w += b3 ? vB3.w : 0.f;

            // ---- advance both walkers (from unclamped positions) ----
            int aX4 = aX3 + 1, aT4 = aT3; if (aX4 >= x1A) { aX4 = x0A; ++aT4; }
            xxA = aX4; yyA = aT4;
            int bX4 = bX3 + 1, bT4 = bT3; if (bX4 >= x1B) { bX4 = x0B; ++bT4; }
            xxB = bX4; yyB = bT4;
            lenA -= 4; lenB -= 4;
        }

        // combine the 4 quarter-sums per cell; all lanes end with full sums
        #pragma unroll
        for (int msk = 16; msk < 64; msk <<= 1) {
            accA.x += __shfl_xor(accA.x, msk, 64);
            accA.y += __shfl_xor(accA.y, msk, 64);
            accA.z += __shfl_xor(accA.z, msk, 64);
            accA.w += __shfl_xor(accA.w, msk, 64);
            accB.x += __shfl_xor(accB.x, msk, 64);
            accB.y += __shfl_xor(accB.y, msk, 64);
            accB.z += __shfl_xor(accB.z, msk, 64);
            accB.w += __shfl_xor(accB.w, msk, 64);
        }

        if (lane < 16) {
            const float invA = 1.f / (float)npxA;
            float4 meanA = make_float4(accA.x * invA, accA.y * invA,
                                       accA.z * invA, accA.w * invA);
            const int oA = anchor_mode ? (y0A * GW + x0A) * 16 + lane
                                       : cellA * 16 + lane;
            dst[oA] = meanA;
            if (hasB) {
                const float invB = 1.f / (float)npxB;
                float4 meanB = make_float4(accB.x * invB, accB.y * invB,
                                           accB.z * invB, accB.w * invB);
                const int oB = anchor_mode ? (y0B * GW + x0B) * 16 + lane
                                           : cellB * 16 + lane;
                dst[oB] = meanB;
            }
        }

        if (!have_next) break;
        cellA = nextA;
        y0A = py0A; y1A = py1A; x0A = px0A; x1A = px1A;   // consume prefetch
        y0B = py0B; y1B = py1B; x0B = px0B; x1B = px1B;
    }
}

// Dense streaming broadcast, means from ws. NONTEMPORAL out stores (147 MB
// write-once). Grid MUST be 2048x256: 768*768*16 / (2048*256) = 18/thread.
__global__ __launch_bounds__(256) void bcast_ws(float4* __restrict__ out,
                                                const float4* __restrict__ means,
                                                const int* __restrict__ ws) {
    const int ncols = ws[OFF_NCOLS];
    int g = blockIdx.x * 256 + threadIdx.x;
    #pragma unroll 6
    for (int it = 0; it < 18; ++it, g += 2048 * 256) {
        const int p  = g >> 4;
        const int cq = g & 15;
        const int y  = p / GW;              // constant divisor -> magic mul
        const int x  = p - y * GW;
        const int rid = ws[OFF_ROWID + y];
        const int cid = ws[OFF_COLID + x];
        const float4 v = means[(rid * ncols + cid) * 16 + cq];
        __builtin_nontemporal_store(*(const f32x4*)&v, (f32x4*)&out[g]);
    }
}

// Last-resort broadcast: means live at each cell's anchor pixel inside out.
__global__ __launch_bounds__(256) void bcast_anchor(float4* out,
                                                    const int* __restrict__ ws) {
    int g = blockIdx.x * 256 + threadIdx.x;
    for (int it = 0; it < 18; ++it, g += 2048 * 256) {
        const int p  = g >> 4;
        const int cq = g & 15;
        const int y  = p / GW;
        const int x  = p - y * GW;
        const int rid = ws[OFF_ROWID + y];
        const int cid = ws[OFF_COLID + x];
        const int ya  = ws[OFF_ROWSTART + rid];
        const int xa  = ws[OFF_COLSTART + cid];
        out[g] = out[(ya * GW + xa) * 16 + cq];
    }
}

extern "C" void kernel_launch(void* const* d_in, const int* in_sizes, int n_in,
                              void* d_out, int out_size, void* d_ws, size_t ws_size,
                              hipStream_t stream) {
    const float* in  = (const float*)d_in[0];   // [1,768,768,64] fp32
    const int* hmask = (const int*)d_in[1];     // [1,768] int32
    const int* vmask = (const int*)d_in[2];     // [1,768] int32
    float* out = (float*)d_out;                 // [1,768,768,64] fp32
    int* ws = (int*)d_ws;

    seg_scan<<<2, GH, 0, stream>>>(hmask, vmask, ws);

    const size_t need_means = (size_t)OFF_MEANS * 4 + MEANS_F4 * 16;
    if (ws_size >= need_means) {
        float4* means = (float4*)(ws + OFF_MEANS);
        cell_mean4<<<2048, 256, 0, stream>>>((const float4*)in, means, ws, 0);
        bcast_ws<<<2048, 256, 0, stream>>>((float4*)out, means, ws);
    } else {
        cell_mean4<<<2048, 256, 0, stream>>>((const float4*)in, (float4*)out, ws, 1);
        bcast_anchor<<<2048, 256, 0, stream>>>((float4*)out, ws);
    }
}